// Round 1
// baseline (430.877 us; speedup 1.0000x reference)
//
#include <hip/hip_runtime.h>
#include <hip/hip_bf16.h>
#include <math.h>

// Problem constants (from reference)
#define BB 2
#define LL 2048
#define DMODEL 1024
#define DINNER 2048
#define DSTATE 16
#define DCONV 4
#define DTRANK 64
#define MROWS (BB * LL)          // 4096
#define XPROJ_N (DTRANK + 2 * DSTATE)  // 96

// scan segmentation: SEG=64, 16 states/thread, 1024 blocks = 4 waves/SIMD.
#define SEG 64
#define LS (LL / SEG)            // 32

// x_proj split-K
#define XKSPLIT 8
#define XKC (DINNER / XKSPLIT)   // 256

typedef unsigned short ushort_t;
typedef short s8v __attribute__((ext_vector_type(8)));   // 8 x bf16 (4 VGPRs)
typedef float f4v __attribute__((ext_vector_type(4)));   // 4 x fp32 acc

__device__ __forceinline__ float siluf(float x) {
    return x / (1.f + expf(-x));
}
__device__ __forceinline__ float softplusf(float x) {
    return fmaxf(x, 0.f) + log1pf(expf(-fabsf(x)));
}
__device__ __forceinline__ ushort_t f32_to_bf16(float f) {
    unsigned u = __builtin_bit_cast(unsigned, f);
    unsigned r = (u + 0x7FFFu + ((u >> 16) & 1u)) >> 16;   // RNE
    return (ushort_t)r;
}
__device__ __forceinline__ float bf16_to_f32(ushort_t u) {
    return __builtin_bit_cast(float, ((unsigned)u) << 16);
}

// -------------------------------------------------------------------------
// Fused prep: all fp32->bf16 weight/input casts + xdbl zeroing, one launch.
// -------------------------------------------------------------------------
__global__ __launch_bounds__(256) void prep_kernel(
    const float* __restrict__ x, const float* __restrict__ ipw,
    const float* __restrict__ sow, const float* __restrict__ fw,
    const float* __restrict__ xpw, const float* __restrict__ dtw,
    ushort_t* __restrict__ x_bf, ushort_t* __restrict__ ipw_bf,
    ushort_t* __restrict__ sow_bf, ushort_t* __restrict__ fw_bf,
    ushort_t* __restrict__ xpw_bf, ushort_t* __restrict__ dtw_bf,
    float4* __restrict__ xdbl_zero)
{
    const long i = ((long)blockIdx.x * 256 + threadIdx.x) * 4;
    const float* src; ushort_t* dst; long off;
    if      (i < 4194304L)  { src = x;   dst = x_bf;   off = i; }
    else if (i < 8388608L)  { src = ipw; dst = ipw_bf; off = i - 4194304L; }
    else if (i < 10485760L) { src = sow; dst = sow_bf; off = i - 8388608L; }
    else if (i < 11534336L) { src = fw;  dst = fw_bf;  off = i - 10485760L; }
    else if (i < 11730944L) { src = xpw; dst = xpw_bf; off = i - 11534336L; }
    else if (i < 11862016L) { src = dtw; dst = dtw_bf; off = i - 11730944L; }
    else { xdbl_zero[(i - 11862016L) >> 2] = make_float4(0.f, 0.f, 0.f, 0.f); return; }
    const float4 v = *reinterpret_cast<const float4*>(src + off);
    ushort_t o[4] = {f32_to_bf16(v.x), f32_to_bf16(v.y),
                     f32_to_bf16(v.z), f32_to_bf16(v.w)};
    *reinterpret_cast<uint2*>(dst + off) = *reinterpret_cast<uint2*>(o);
}

// cast xdbl[:, 0:64] (ld 96, fp32) -> dt_bf [MROWS,64]
__global__ __launch_bounds__(256) void cast_dt_kernel(
    const float* __restrict__ xdbl, ushort_t* __restrict__ dtbf)
{
    const int i4 = (blockIdx.x * 256 + threadIdx.x) * 4;   // over MROWS*64
    const int row = i4 >> 6;
    const int col = i4 & 63;
    const float4 v = *reinterpret_cast<const float4*>(&xdbl[(size_t)row * XPROJ_N + col]);
    ushort_t o[4] = {f32_to_bf16(v.x), f32_to_bf16(v.y),
                     f32_to_bf16(v.z), f32_to_bf16(v.w)};
    *reinterpret_cast<uint2*>(dtbf + i4) = *reinterpret_cast<uint2*>(o);
}

#define TBK 32

// -------------------------------------------------------------------------
// 256x256-tile 8-phase bf16 MFMA GEMM (learn_hip m201 template, plain HIP).
// BK=64, 8 waves (2M x 4N), per-wave output 128x64, acc[8][4].
// LDS = 128 KiB: per operand a 4-deep ring of 16KB half-tiles
//   (half-tile = 128 rows x 64 k-elems, stored [2 ksteps][128 rows][32 elems],
//    st_16x32 swizzle: byte ^= ((byte>>9)&1)<<5, applied by pre-swizzling the
//    global SOURCE address (global_load_lds dest must stay linear) and by
//    XOR-ing the ds_read address the same way).
// Per K-tile, 4 phases: {ds_read frags | stage 1 half-tile | bar | lgkmcnt(0)
//   | setprio(1) 16xMFMA setprio(0) | bar}; counted vmcnt(6) only at tile
//   boundaries (never 0 in steady state).
// Staging stream: halves ordered [B0,B1,A0,A1]; stage(g) issued at linear
//   phase g-7 -> every ring-slot overwrite is >=1 full barrier after the
//   phase that last reads that slot (B last read P1, A last read P3).
// -------------------------------------------------------------------------
__device__ __forceinline__ void stage_half(
    const ushort_t* __restrict__ A, int lda,
    const ushort_t* __restrict__ B, int ldb,
    int m0, int n0, int g, char* sb, int tid, int w)
{
    const bool isA  = (g & 2) != 0;      // g%4: 0,1 = B half0/1 ; 2,3 = A half0/1
    const int  half = g & 1;
    const int  tau  = g >> 2;            // K-tile index
    const int  slot = ((tau << 1) + half) & 3;
    // per-thread linear dest (within 16KB half) = (j*512 + tid)*16 ; the
    // st_16x32 XOR only flips byte-bit5, i.e. k-chunk bit, when row-bit3 set:
    const int  r  = tid >> 2;                                        // 0..127
    const int  kb = ((tid & 3) << 4) ^ (((tid >> 5) & 1) << 5);      // 0..63 bytes
    const int  ke = kb >> 1;                                         // elems
    const ushort_t* src = isA ? A : B;
    const int  ld   = isA ? lda : ldb;
    const int  row0 = (isA ? m0 : n0) + half * 128;
    char* dst = sb + (isA ? 0 : 65536) + slot * 16384 + (w << 10);
    const ushort_t* gp = src + (size_t)(row0 + r) * ld + tau * 64 + ke;
    __builtin_amdgcn_global_load_lds(
        (const __attribute__((address_space(1))) unsigned int*)gp,
        (__attribute__((address_space(3))) unsigned int*)dst, 16, 0, 0);
    __builtin_amdgcn_global_load_lds(
        (const __attribute__((address_space(1))) unsigned int*)(gp + 32),
        (__attribute__((address_space(3))) unsigned int*)(dst + 8192), 16, 0, 0);
}

#define MFMA_QUAD(MB, NB)                                                     \
    _Pragma("unroll")                                                         \
    for (int mi = 0; mi < 4; ++mi)                                            \
      _Pragma("unroll")                                                       \
      for (int nj = 0; nj < 2; ++nj)                                          \
        _Pragma("unroll")                                                     \
        for (int ks = 0; ks < 2; ++ks)                                        \
          acc[(MB) + mi][(NB) + nj] = __builtin_amdgcn_mfma_f32_16x16x32_bf16(\
              a[mi][ks], b[(NB) + nj][ks], acc[(MB) + mi][(NB) + nj], 0, 0, 0);

__global__ void __launch_bounds__(512, 2) gemm256_bf16_mfma(
    const ushort_t* __restrict__ A, int lda,
    const ushort_t* __restrict__ B, int ldb,
    int K,
    void* __restrict__ C0v, void* __restrict__ C1v, int splitN, int ldc,
    const float* __restrict__ bias, int act, int store_bf16)
{
    __shared__ __align__(16) ushort_t smem[65536];   // 128 KiB: A ring | B ring
    char* sb = (char*)smem;

    const int tid  = threadIdx.x;
    const int lane = tid & 63;
    const int w    = tid >> 6;            // wave 0..7
    const int wm   = w & 1;               // M-wave: rows wm*128..+127
    const int wn   = w >> 1;              // N-wave: cols wn*64..+63
    const int m0   = blockIdx.y * 256;
    const int n0   = blockIdx.x * 256;
    const int fr   = lane & 15;
    const int kg   = lane >> 4;           // k-chunk 0..3 (8 elems)
    const int NT   = K >> 6;              // K-tiles (BK=64); requires NT >= 3
    const int glim = NT << 2;

    // swizzled per-lane ds_read offset within a [128][32]-elem panel
    const int laneoff = fr * 64 + ((kg * 16) ^ ((fr & 8) << 2));
    const int halfB   = wn >> 1;          // which B half this wave reads

    f4v acc[8][4] = {};
    s8v a[4][2], b[4][2];

    // ---- prologue: prime 7 half-tiles (tile0 full + 3 of tile1) ----
    #pragma unroll
    for (int g = 0; g < 7; ++g)
        stage_half(A, lda, B, ldb, m0, n0, g, sb, tid, w);
    asm volatile("s_waitcnt vmcnt(6)" ::: "memory");   // tile 0 fully landed
    __builtin_amdgcn_s_barrier();

    for (int t = 0; t < NT; ++t) {
        const int slotA = ((t << 1) + wm) & 3;
        const int slotB = ((t << 1) + halfB) & 3;
        const char* sa = sb + slotA * 16384;
        const char* sB = sb + 65536 + slotB * 16384 + ((wn & 1) << 12);
        const int gb = (t << 2) + 7;

        // ---- P1: ds_read A(mi0-3)+B(all) (16 reads); stage t+1.A1 ----
        #pragma unroll
        for (int mi = 0; mi < 4; ++mi)
            #pragma unroll
            for (int ks = 0; ks < 2; ++ks)
                a[mi][ks] = *reinterpret_cast<const s8v*>(
                    sa + ks * 8192 + mi * 1024 + laneoff);
        #pragma unroll
        for (int nj = 0; nj < 4; ++nj)
            #pragma unroll
            for (int ks = 0; ks < 2; ++ks)
                b[nj][ks] = *reinterpret_cast<const s8v*>(
                    sB + ks * 8192 + nj * 1024 + laneoff);
        if (gb < glim) stage_half(A, lda, B, ldb, m0, n0, gb, sb, tid, w);
        __builtin_amdgcn_s_barrier();
        asm volatile("s_waitcnt lgkmcnt(0)" ::: "memory");
        __builtin_amdgcn_sched_barrier(0);
        __builtin_amdgcn_s_setprio(1);
        MFMA_QUAD(0, 0)
        __builtin_amdgcn_s_setprio(0);
        __builtin_amdgcn_s_barrier();

        // ---- P2: stage t+2.B0 (slot held tile t B0, read done in P1) ----
        if (gb + 1 < glim) stage_half(A, lda, B, ldb, m0, n0, gb + 1, sb, tid, w);
        __builtin_amdgcn_s_barrier();
        __builtin_amdgcn_s_setprio(1);
        MFMA_QUAD(0, 2)
        __builtin_amdgcn_s_setprio(0);
        __builtin_amdgcn_s_barrier();

        // ---- P3: ds_read A(mi4-7) (8 reads); stage t+2.B1 ----
        #pragma unroll
        for (int mi = 0; mi < 4; ++mi)
            #pragma unroll
            for (int ks = 0; ks < 2; ++ks)
                a[mi][ks] = *reinterpret_cast<const s8v*>(
                    sa + ks * 8192 + (mi + 4) * 1024 + laneoff);
        if (gb + 2 < glim) stage_half(A, lda, B, ldb, m0, n0, gb + 2, sb, tid, w);
        __builtin_amdgcn_s_barrier();
        asm volatile("s_waitcnt lgkmcnt(0)" ::: "memory");
        __builtin_amdgcn_sched_barrier(0);
        __builtin_amdgcn_s_setprio(1);
        MFMA_QUAD(4, 0)
        __builtin_amdgcn_s_setprio(0);
        __builtin_amdgcn_s_barrier();

        // ---- P4: stage t+2.A0 (slot held tile t A0, read done in P3) ----
        if (gb + 3 < glim) stage_half(A, lda, B, ldb, m0, n0, gb + 3, sb, tid, w);
        __builtin_amdgcn_s_barrier();
        __builtin_amdgcn_s_setprio(1);
        MFMA_QUAD(4, 2)
        __builtin_amdgcn_s_setprio(0);
        // K-tile boundary: counted drain -> tile t+1 guaranteed landed
        if (t < NT - 2) {
            asm volatile("s_waitcnt vmcnt(6)" ::: "memory");
            __builtin_amdgcn_s_barrier();
        } else if (t == NT - 2) {
            asm volatile("s_waitcnt vmcnt(0)" ::: "memory");
            __builtin_amdgcn_s_barrier();
        }
        // t == NT-1: last tile, epilogue follows (no LDS reuse)
    }

    // epilogue: C/D layout col=lane&15, row=(lane>>4)*4+reg  [m89]
    const int rbase = (lane >> 4) * 4;
    const int cbase = lane & 15;
    #pragma unroll
    for (int mi = 0; mi < 8; ++mi) {
        #pragma unroll
        for (int nj = 0; nj < 4; ++nj) {
            const int row = m0 + wm * 128 + mi * 16 + rbase;
            const int col = n0 + wn * 64 + nj * 16 + cbase;
            void* Cp = C0v;
            int c2 = col;
            if (C1v && col >= splitN) { Cp = C1v; c2 = col - splitN; }
            const float bv = bias ? bias[col] : 0.f;
            #pragma unroll
            for (int r = 0; r < 4; ++r) {
                float v = acc[mi][nj][r] + bv;
                if (act == 1) v = siluf(v);
                else if (act == 2) v = softplusf(v);
                if (store_bf16)
                    ((ushort_t*)Cp)[(size_t)(row + r) * ldc + c2] = f32_to_bf16(v);
                else
                    ((float*)Cp)[(size_t)(row + r) * ldc + c2] = v;
            }
        }
    }
}

// -------------------------------------------------------------------------
// 64x128-tile variant for the N<=2048 GEMMs (dt_proj/out_proj/final).
// 512 threads = 8 waves, 2x4 wave grid, 32x32/wave, acc[2][2].
// -------------------------------------------------------------------------
#define UM 64
#define UN 128

__global__ __launch_bounds__(512) void gemm64_bf16_mfma(
    const ushort_t* __restrict__ A, int lda,
    const ushort_t* __restrict__ B, int ldb,
    int K,
    void* __restrict__ C0v, int ldc,
    const float* __restrict__ bias, int act, int store_bf16)
{
    __shared__ __align__(16) ushort_t As[UM * TBK];   // 4 KB
    __shared__ __align__(16) ushort_t Bs[UN * TBK];   // 8 KB

    const int tid  = threadIdx.x;
    const int lane = tid & 63;
    const int w    = tid >> 6;            // wave 0..7
    const int wm   = w & 1;               // wave row (0..1) -> 32 rows
    const int wn   = w >> 1;              // wave col (0..3) -> 32 cols
    const int m0   = blockIdx.y * UM;
    const int n0   = blockIdx.x * UN;

    const int srow = lane >> 2;
    const int scol = (lane & 3) * 8;

    f4v acc[2][2] = {};

    for (int k0 = 0; k0 < K; k0 += TBK) {
        if (w < 4) {   // A chunks 0..3 (64 rows)
            const ushort_t* ga = A + (size_t)(m0 + w * 16 + srow) * lda + k0 + scol;
            __builtin_amdgcn_global_load_lds(
                (const __attribute__((address_space(1))) unsigned int*)ga,
                (__attribute__((address_space(3))) unsigned int*)(As + w * 512),
                16, 0, 0);
        }
        {   // B chunks 0..7 (128 rows)
            const ushort_t* gb = B + (size_t)(n0 + w * 16 + srow) * ldb + k0 + scol;
            __builtin_amdgcn_global_load_lds(
                (const __attribute__((address_space(1))) unsigned int*)gb,
                (__attribute__((address_space(3))) unsigned int*)(Bs + w * 512),
                16, 0, 0);
        }
        __syncthreads();

        const int fr = lane & 15;
        const int kg = lane >> 4;
        s8v a[2], b[2];
        #pragma unroll
        for (int t = 0; t < 2; ++t)
            a[t] = *reinterpret_cast<const s8v*>(As + (wm * 32 + t * 16 + fr) * TBK + kg * 8);
        #pragma unroll
        for (int t = 0; t < 2; ++t)
            b[t] = *reinterpret_cast<const s8v*>(Bs + (wn * 32 + t * 16 + fr) * TBK + kg * 8);
        #pragma unroll
        for (int i = 0; i < 2; ++i)
            #pragma unroll
            for (int j = 0; j < 2; ++j)
                acc[i][j] = __builtin_amdgcn_mfma_f32_16x16x32_bf16(
                    a[i], b[j], acc[i][j], 0, 0, 0);
        __syncthreads();
    }

    const int rbase = (lane >> 4) * 4;
    const int cbase = lane & 15;
    #pragma unroll
    for (int i = 0; i < 2; ++i) {
        #pragma unroll
        for (int j = 0; j < 2; ++j) {
            const int row = m0 + wm * 32 + i * 16 + rbase;
            const int col = n0 + wn * 32 + j * 16 + cbase;
            const float bv = bias ? bias[col] : 0.f;
            #pragma unroll
            for (int r = 0; r < 4; ++r) {
                float v = acc[i][j][r] + bv;
                if (act == 1) v = siluf(v);
                else if (act == 2) v = softplusf(v);
                if (store_bf16)
                    ((ushort_t*)C0v)[(size_t)(row + r) * ldc + col] = f32_to_bf16(v);
                else
                    ((float*)C0v)[(size_t)(row + r) * ldc + col] = v;
            }
        }
    }
}

// -------------------------------------------------------------------------
// x_proj skinny GEMM, split-K with fp32 atomic reduction.
// -------------------------------------------------------------------------
__global__ __launch_bounds__(256) void xproj_mfma(
    const ushort_t* __restrict__ A, const ushort_t* __restrict__ Bw,
    float* __restrict__ Cout)
{
    __shared__ __align__(16) ushort_t As[64 * 32];   // 4 KB
    __shared__ __align__(16) ushort_t Bs[96 * 32];   // 6 KB

    const int tid = threadIdx.x;
    const int lane = tid & 63;
    const int w = tid >> 6;
    const int kbase = blockIdx.x * XKC;
    const int m0 = blockIdx.y * 64;

    const int srow = lane >> 2;
    const int scol = (lane & 3) * 8;

    f4v acc[6] = {};

    for (int k0 = kbase; k0 < kbase + XKC; k0 += 32) {
        {
            const ushort_t* ga = A + (size_t)(m0 + w * 16 + srow) * DINNER + k0 + scol;
            __builtin_amdgcn_global_load_lds(
                (const __attribute__((address_space(1))) unsigned int*)ga,
                (__attribute__((address_space(3))) unsigned int*)(As + (w * 16) * 32),
                16, 0, 0);
        }
        {
            const ushort_t* gb = Bw + (size_t)(w * 16 + srow) * DINNER + k0 + scol;
            __builtin_amdgcn_global_load_lds(
                (const __attribute__((address_space(1))) unsigned int*)gb,
                (__attribute__((address_space(3))) unsigned int*)(Bs + (w * 16) * 32),
                16, 0, 0);
        }
        if (w < 2) {
            const ushort_t* gb = Bw + (size_t)((4 + w) * 16 + srow) * DINNER + k0 + scol;
            __builtin_amdgcn_global_load_lds(
                (const __attribute__((address_space(1))) unsigned int*)gb,
                (__attribute__((address_space(3))) unsigned int*)(Bs + ((4 + w) * 16) * 32),
                16, 0, 0);
        }
        __syncthreads();

        const int fr = lane & 15;
        const int kg = lane >> 4;
        const s8v a = *reinterpret_cast<const s8v*>(As + (w * 16 + fr) * 32 + kg * 8);
        #pragma unroll
        for (int j = 0; j < 6; ++j) {
            const s8v b = *reinterpret_cast<const s8v*>(Bs + (j * 16 + fr) * 32 + kg * 8);
            acc[j] = __builtin_amdgcn_mfma_f32_16x16x32_bf16(a, b, acc[j], 0, 0, 0);
        }
        __syncthreads();
    }

    const int rbase = (lane >> 4) * 4;
    const int cb = lane & 15;
    #pragma unroll
    for (int j = 0; j < 6; ++j)
        #pragma unroll
        for (int r = 0; r < 4; ++r)
            atomicAdd(&Cout[(size_t)(m0 + w * 16 + rbase + r) * XPROJ_N + j * 16 + cb],
                      acc[j][r]);
}

// -------------------------------------------------------------------------
// Causal depthwise conv1d (W=4) + bias + SiLU; bf16 in, bf16 out.
// -------------------------------------------------------------------------
__global__ __launch_bounds__(256) void conv_silu_kernel(
    const ushort_t* __restrict__ xin, const float* __restrict__ w,
    const float* __restrict__ b, ushort_t* __restrict__ xcbf)
{
    const int idx = blockIdx.x * blockDim.x + threadIdx.x;
    const int c = idx % DINNER;
    const int bl = idx / DINNER;
    const int l = bl % LL;
    const int bb = bl / LL;
    if (bb >= BB) return;

    const ushort_t* xp = xin + (size_t)bb * LL * DINNER + c;
    float acc = b[c];
    #pragma unroll
    for (int k = 0; k < DCONV; ++k) {
        const int ll = l - (DCONV - 1) + k;
        if (ll >= 0)
            acc = fmaf(bf16_to_f32(xp[(size_t)ll * DINNER]), w[c * DCONV + k], acc);
    }
    xcbf[idx] = f32_to_bf16(siluf(acc));
}

// -------------------------------------------------------------------------
// Segmented selective scan, SEG=64, 16 states/thread (round-8 form).
// Grid (DINNER/256, SEG, BB) = 1024 blocks = 4 waves/SIMD.
// B/C via converged global float4 loads (L1 broadcast).
// -------------------------------------------------------------------------
__global__ __launch_bounds__(256) void scan_part1(
    const ushort_t* __restrict__ delta, const float* __restrict__ xdbl,
    const ushort_t* __restrict__ xc, const float* __restrict__ A_log,
    float* __restrict__ hloc, float* __restrict__ decay)
{
    const int d = blockIdx.x * 256 + threadIdx.x;
    const int seg = blockIdx.y;
    const int b = blockIdx.z;
    const int t0 = seg * LS;

    float Ad[DSTATE];
    #pragma unroll
    for (int n = 0; n < DSTATE; ++n)
        Ad[n] = -expf(A_log[d * DSTATE + n]);

    float h[DSTATE];
    #pragma unroll
    for (int n = 0; n < DSTATE; ++n) h[n] = 0.f;

    const ushort_t* dp = delta + ((size_t)b * LL) * DINNER + d;
    const ushort_t* up = xc    + ((size_t)b * LL) * DINNER + d;
    const float*    xb = xdbl  + ((size_t)b * LL) * XPROJ_N;

    float sum_dl = 0.f;
    for (int t = t0; t < t0 + LS; ++t) {
        const float dl = bf16_to_f32(dp[(size_t)t * DINNER]);
        const float u  = bf16_to_f32(up[(size_t)t * DINNER]);
        const float4 b0 = *reinterpret_cast<const float4*>(&xb[t * XPROJ_N + DTRANK + 0]);
        const float4 b1 = *reinterpret_cast<const float4*>(&xb[t * XPROJ_N + DTRANK + 4]);
        const float4 b2 = *reinterpret_cast<const float4*>(&xb[t * XPROJ_N + DTRANK + 8]);
        const float4 b3 = *reinterpret_cast<const float4*>(&xb[t * XPROJ_N + DTRANK + 12]);
        const float Bv[DSTATE] = {b0.x, b0.y, b0.z, b0.w, b1.x, b1.y, b1.z, b1.w,
                                  b2.x, b2.y, b2.z, b2.w, b3.x, b3.y, b3.z, b3.w};
        const float dlu = dl * u;
        sum_dl += dl;
        #pragma unroll
        for (int n = 0; n < DSTATE; ++n)
            h[n] = __expf(dl * Ad[n]) * h[n] + dlu * Bv[n];
    }

    const size_t base = (((size_t)b * SEG + seg) * DSTATE) * DINNER + d;
    #pragma unroll
    for (int n = 0; n < DSTATE; ++n) {
        hloc[base + (size_t)n * DINNER]  = h[n];
        decay[base + (size_t)n * DINNER] = __expf(Ad[n] * sum_dl);
    }
}

// In-place combine: hloc[s] is REPLACED by the true h_start of segment s.
__global__ __launch_bounds__(256) void scan_combine(
    float* __restrict__ hloc, const float* __restrict__ decay)
{
    const int idx = blockIdx.x * 256 + threadIdx.x;
    const int d = idx % DINNER;
    const int n = (idx / DINNER) % DSTATE;
    const int b = idx / (DINNER * DSTATE);
    if (b >= BB) return;

    float carry = 0.f;
    for (int s = 0; s < SEG; ++s) {
        const size_t off = (((size_t)b * SEG + s) * DSTATE + n) * DINNER + d;
        const float hl = hloc[off];
        hloc[off] = carry;
        carry = decay[off] * carry + hl;
    }
}

__global__ __launch_bounds__(256) void scan_part2(
    const ushort_t* __restrict__ delta, const float* __restrict__ xdbl,
    const ushort_t* __restrict__ xc, const ushort_t* __restrict__ z,
    const float* __restrict__ A_log, const float* __restrict__ Dvec,
    const float* __restrict__ hstart, ushort_t* __restrict__ ybf)
{
    const int d = blockIdx.x * 256 + threadIdx.x;
    const int seg = blockIdx.y;
    const int b = blockIdx.z;
    const int t0 = seg * LS;

    float Ad[DSTATE];
    #pragma unroll
    for (int n = 0; n < DSTATE; ++n)
        Ad[n] = -expf(A_log[d * DSTATE + n]);

    float h[DSTATE];
    const size_t hbase = (((size_t)b * SEG + seg) * DSTATE) * DINNER + d;
    #pragma unroll
    for (int n = 0; n < DSTATE; ++n)
        h[n] = hstart[hbase + (size_t)n * DINNER];

    const float Dd = Dvec[d];
    const ushort_t* dp = delta + ((size_t)b * LL) * DINNER + d;
    const ushort_t* up = xc    + ((size_t)b * LL) * DINNER + d;
    const float*    xb = xdbl  + ((size_t)b * LL) * XPROJ_N;
    const ushort_t* zp = z     + ((size_t)b * LL) * DINNER + d;
    ushort_t*       yp = ybf   + ((size_t)b * LL) * DINNER + d;

    for (int t = t0; t < t0 + LS; ++t) {
        const float dl = bf16_to_f32(dp[(size_t)t * DINNER]);
        const float u  = bf16_to_f32(up[(size_t)t * DINNER]);
        const float zv = bf16_to_f32(zp[(size_t)t * DINNER]);
        const float4 b0 = *reinterpret_cast<const float4*>(&xb[t * XPROJ_N + DTRANK + 0]);
        const float4 b1 = *reinterpret_cast<const float4*>(&xb[t * XPROJ_N + DTRANK + 4]);
        const float4 b2 = *reinterpret_cast<const float4*>(&xb[t * XPROJ_N + DTRANK + 8]);
        const float4 b3 = *reinterpret_cast<const float4*>(&xb[t * XPROJ_N + DTRANK + 12]);
        const float4 c0 = *reinterpret_cast<const float4*>(&xb[t * XPROJ_N + DTRANK + DSTATE + 0]);
        const float4 c1 = *reinterpret_cast<const float4*>(&xb[t * XPROJ_N + DTRANK + DSTATE + 4]);
        const float4 c2 = *reinterpret_cast<const float4*>(&xb[t * XPROJ_N + DTRANK + DSTATE + 8]);
        const float4 c3 = *reinterpret_cast<const float4*>(&xb[t * XPROJ_N + DTRANK + DSTATE + 12]);
        const float Bv[DSTATE] = {b0.x, b0.y, b0.z, b0.w, b1.x, b1.y, b1.z, b1.w,
                                  b2.x, b2.y, b2.z, b2.w, b3.x, b3.y, b3.z, b3.w};
        const float Cv[DSTATE] = {c0.x, c0.y, c0.z, c0.w, c1.x, c1.y, c1.z, c1.w,
                                  c2.x, c2.y, c2.z, c2.w, c3.x, c3.y, c3.z, c3.w};
        const float dlu = dl * u;
        float y = 0.f;
        #pragma unroll
        for (int n = 0; n < DSTATE; ++n) {
            h[n] = __expf(dl * Ad[n]) * h[n] + dlu * Bv[n];
            y = fmaf(h[n], Cv[n], y);
        }
        yp[(size_t)t * DINNER] = f32_to_bf16((y + u * Dd) * siluf(zv));
    }
}

// -------------------------------------------------------------------------
extern "C" void kernel_launch(void* const* d_in, const int* in_sizes, int n_in,
                              void* d_out, int out_size, void* d_ws, size_t ws_size,
                              hipStream_t stream) {
    const float* x         = (const float*)d_in[0];
    const float* in_proj_w = (const float*)d_in[1];
    const float* conv_w    = (const float*)d_in[2];
    const float* conv_b    = (const float*)d_in[3];
    const float* x_proj_w  = (const float*)d_in[4];
    const float* dt_proj_w = (const float*)d_in[5];
    const float* dt_proj_b = (const float*)d_in[6];
    const float* A_log     = (const float*)d_in[7];
    const float* Dvec      = (const float*)d_in[8];
    const float* ssm_out_w = (const float*)d_in[9];
    const float* final_w   = (const float*)d_in[10];
    const float* final_b   = (const float*)d_in[11];
    float* out = (float*)d_out;

    // ---- workspace layout, 126 MB total ----
    const size_t MB = 1024 * 1024;
    char* base = (char*)d_ws;
    ushort_t* xin_bf   = (ushort_t*)(base);              // 16 MB [in_proj -> conv]
    ushort_t* z_bf     = (ushort_t*)(base + 16 * MB);    // 16 MB [in_proj -> scan2]
    ushort_t* xc_bf    = (ushort_t*)(base + 32 * MB);    // 16 MB [conv -> xproj/scan]
    ushort_t* delta_bf = (ushort_t*)(base + 48 * MB);    // 16 MB [dt_proj -> scan]
    float*    xdbl     = (float*)(base + 64 * MB);       // 1.5 MB [xproj -> scan]
    ushort_t* x_bf     = (ushort_t*)(base + 78 * MB);    // 8 MB [prep -> in_proj]
    ushort_t* ipw_bf   = (ushort_t*)(base + 86 * MB);    // 8 MB [prep -> in_proj]
    ushort_t* sow_bf   = (ushort_t*)(base + 94 * MB);    // 4 MB
    ushort_t* fw_bf    = (ushort_t*)(base + 98 * MB);    // 2 MB
    ushort_t* xpw_bf   = (ushort_t*)(base + 100 * MB);   // 384 KB
    ushort_t* dtw_bf   = (ushort_t*)(base + 100 * MB + 512 * 1024);  // 256 KB
    ushort_t* dt_bf    = (ushort_t*)(base + 101 * MB);   // 512 KB
    ushort_t* y_bf     = (ushort_t*)(base + 102 * MB);   // 16 MB
    ushort_t* outb_bf  = (ushort_t*)(base + 118 * MB);   // 8 MB
    // scan scratch (16 MB each), OVERLAID on dead regions:
    float* hloc  = (float*)(base);            // 16 MB over xin_bf (dead after conv)
    float* decay = (float*)(base + 78 * MB);  // 16 MB over x_bf/ipw_bf (dead after in_proj)

    // 0) fused casts + xdbl zeroing (one launch; 11968 blocks)
    prep_kernel<<<11968, 256, 0, stream>>>(
        x, in_proj_w, ssm_out_w, final_w, x_proj_w, dt_proj_w,
        x_bf, ipw_bf, sow_bf, fw_bf, xpw_bf, dtw_bf, (float4*)xdbl);

    // 1) in_proj (256^2 8-phase MFMA): [xin_bf | z_bf] = x @ in_proj_w^T
    //    (M=4096, N=4096, K=1024; grid 16x16 = 256 blocks = 1/CU)
    gemm256_bf16_mfma<<<dim3((2 * DINNER) / 256, MROWS / 256), 512, 0, stream>>>(
        x_bf, DMODEL, ipw_bf, DMODEL, DMODEL,
        xin_bf, z_bf, DINNER, DINNER, nullptr, 0, 1);

    // 2) causal depthwise conv + SiLU -> xc_bf
    conv_silu_kernel<<<(MROWS * DINNER) / 256, 256, 0, stream>>>(
        xin_bf, conv_w, conv_b, xc_bf);

    // 3) x_proj (bf16 MFMA, split-K atomic): xdbl = xc @ x_proj_w^T (M=4096,N=96,K=2048)
    xproj_mfma<<<dim3(XKSPLIT, MROWS / 64), 256, 0, stream>>>(xc_bf, xpw_bf, xdbl);

    // 4) dt_proj (bf16 MFMA, 64-row tile): delta_bf = softplus(dt @ dt_proj_w^T + b)
    cast_dt_kernel<<<(MROWS * DTRANK / 4) / 256, 256, 0, stream>>>(xdbl, dt_bf);
    gemm64_bf16_mfma<<<dim3(DINNER / UN, MROWS / UM), 512, 0, stream>>>(
        dt_bf, DTRANK, dtw_bf, DTRANK, DTRANK,
        delta_bf, DINNER, dt_proj_b, 2, 1);

    // 5) segmented selective scan + skip + gate -> y_bf
    scan_part1<<<dim3(DINNER / 256, SEG, BB), 256, 0, stream>>>(
        delta_bf, xdbl, xc_bf, A_log, hloc, decay);
    scan_combine<<<(BB * DSTATE * DINNER) / 256, 256, 0, stream>>>(hloc, decay);
    scan_part2<<<dim3(DINNER / 256, SEG, BB), 256, 0, stream>>>(
        delta_bf, xdbl, xc_bf, z_bf, A_log, Dvec, hloc, y_bf);

    // 6) out_proj (bf16 MFMA, 64-row tile): outb_bf = y @ ssm_out_w^T (M=4096,N=1024,K=2048)
    gemm64_bf16_mfma<<<dim3(DMODEL / UN, MROWS / UM), 512, 0, stream>>>(
        y_bf, DINNER, sow_bf, DINNER, DINNER,
        outb_bf, DMODEL, nullptr, 0, 1);

    // 7) final (bf16 MFMA, 64-row tile): out = silu(outb @ final_w^T + final_b)
    gemm64_bf16_mfma<<<dim3(DMODEL / UN, MROWS / UM), 512, 0, stream>>>(
        outb_bf, DMODEL, fw_bf, DMODEL, DMODEL,
        out, DMODEL, final_b, 1, 0);
}

// Round 2
// 425.215 us; speedup vs baseline: 1.0133x; 1.0133x over previous
//
#include <hip/hip_runtime.h>
#include <hip/hip_bf16.h>
#include <math.h>

// Problem constants (from reference)
#define BB 2
#define LL 2048
#define DMODEL 1024
#define DINNER 2048
#define DSTATE 16
#define DCONV 4
#define DTRANK 64
#define MROWS (BB * LL)          // 4096
#define XPROJ_N (DTRANK + 2 * DSTATE)  // 96

// scan segmentation: SEG=64, 16 states/thread, 1024 blocks = 4 waves/SIMD.
#define SEG 64
#define LS (LL / SEG)            // 32

// x_proj split-K
#define XKSPLIT 8
#define XKC (DINNER / XKSPLIT)   // 256

typedef unsigned short ushort_t;
typedef short s8v __attribute__((ext_vector_type(8)));   // 8 x bf16 (4 VGPRs)
typedef float f4v __attribute__((ext_vector_type(4)));   // 4 x fp32 acc

__device__ __forceinline__ float siluf(float x) {
    return x / (1.f + expf(-x));
}
__device__ __forceinline__ float softplusf(float x) {
    return fmaxf(x, 0.f) + log1pf(expf(-fabsf(x)));
}
__device__ __forceinline__ ushort_t f32_to_bf16(float f) {
    unsigned u = __builtin_bit_cast(unsigned, f);
    unsigned r = (u + 0x7FFFu + ((u >> 16) & 1u)) >> 16;   // RNE
    return (ushort_t)r;
}
__device__ __forceinline__ float bf16_to_f32(ushort_t u) {
    return __builtin_bit_cast(float, ((unsigned)u) << 16);
}

// -------------------------------------------------------------------------
// Fused prep: all fp32->bf16 weight/input casts + xdbl zeroing, one launch.
// -------------------------------------------------------------------------
__global__ __launch_bounds__(256) void prep_kernel(
    const float* __restrict__ x, const float* __restrict__ ipw,
    const float* __restrict__ sow, const float* __restrict__ fw,
    const float* __restrict__ xpw, const float* __restrict__ dtw,
    ushort_t* __restrict__ x_bf, ushort_t* __restrict__ ipw_bf,
    ushort_t* __restrict__ sow_bf, ushort_t* __restrict__ fw_bf,
    ushort_t* __restrict__ xpw_bf, ushort_t* __restrict__ dtw_bf,
    float4* __restrict__ xdbl_zero)
{
    const long i = ((long)blockIdx.x * 256 + threadIdx.x) * 4;
    const float* src; ushort_t* dst; long off;
    if      (i < 4194304L)  { src = x;   dst = x_bf;   off = i; }
    else if (i < 8388608L)  { src = ipw; dst = ipw_bf; off = i - 4194304L; }
    else if (i < 10485760L) { src = sow; dst = sow_bf; off = i - 8388608L; }
    else if (i < 11534336L) { src = fw;  dst = fw_bf;  off = i - 10485760L; }
    else if (i < 11730944L) { src = xpw; dst = xpw_bf; off = i - 11534336L; }
    else if (i < 11862016L) { src = dtw; dst = dtw_bf; off = i - 11730944L; }
    else { xdbl_zero[(i - 11862016L) >> 2] = make_float4(0.f, 0.f, 0.f, 0.f); return; }
    const float4 v = *reinterpret_cast<const float4*>(src + off);
    ushort_t o[4] = {f32_to_bf16(v.x), f32_to_bf16(v.y),
                     f32_to_bf16(v.z), f32_to_bf16(v.w)};
    *reinterpret_cast<uint2*>(dst + off) = *reinterpret_cast<uint2*>(o);
}

// cast xdbl[:, 0:64] (ld 96, fp32) -> dt_bf [MROWS,64]
__global__ __launch_bounds__(256) void cast_dt_kernel(
    const float* __restrict__ xdbl, ushort_t* __restrict__ dtbf)
{
    const int i4 = (blockIdx.x * 256 + threadIdx.x) * 4;   // over MROWS*64
    const int row = i4 >> 6;
    const int col = i4 & 63;
    const float4 v = *reinterpret_cast<const float4*>(&xdbl[(size_t)row * XPROJ_N + col]);
    ushort_t o[4] = {f32_to_bf16(v.x), f32_to_bf16(v.y),
                     f32_to_bf16(v.z), f32_to_bf16(v.w)};
    *reinterpret_cast<uint2*>(dtbf + i4) = *reinterpret_cast<uint2*>(o);
}

#define TBK 32

// -------------------------------------------------------------------------
// 256x256-tile 8-phase bf16 MFMA GEMM (learn_hip m201 template, plain HIP).
// Round-2 revision: same verified schedule as round 1 (correct, absmax-
// identical), but register-pressure anomaly fixed:
//   * stage is templated on TYPE (g&3 is compile-time at every call site);
//     per-thread global row bases hoisted out of the loop -> no runtime
//     isA/half selects, far fewer live temporaries.
//   * MFMA quad is a template function with plain #pragma unroll -> acc
//     indexing guaranteed static (rule #20), no scratch.
//   * bijective XCD patch swizzle (8 XCDs x 32-block 8x4 patches).
// Schedule (unchanged): BK=64, 8 waves (2M x 4N), per-wave 128x64,
// acc[8][4]; LDS 128 KiB = 2 operands x 4-slot ring of 16KB half-tiles
// [2 ksteps][128 rows][32 elems], st_16x32 swizzle via pre-swizzled global
// source + XOR'd ds_read. 4 phases/K-tile; counted vmcnt(6) at boundaries.
// Staging stream [B0,B1,A0,A1], prefetch C=7 halves ahead.
// -------------------------------------------------------------------------

// TYPE: 0=B0, 1=B1, 2=A0, 3=A1  (TYPE&1 = half). ring/base chosen by caller.
template<int TYPE>
__device__ __forceinline__ void stage_t(
    const ushort_t* __restrict__ base,   // per-thread row base (half 0)
    int ld, int tau, char* ring, int woff)
{
    const int slot = ((tau << 1) + (TYPE & 1)) & 3;
    char* dst = ring + slot * 16384 + woff;
    const ushort_t* gp = base + (size_t)tau * 64
                       + ((TYPE & 1) ? (size_t)128 * ld : 0);
    __builtin_amdgcn_global_load_lds(
        (const __attribute__((address_space(1))) unsigned int*)gp,
        (__attribute__((address_space(3))) unsigned int*)dst, 16, 0, 0);
    __builtin_amdgcn_global_load_lds(
        (const __attribute__((address_space(1))) unsigned int*)(gp + 32),
        (__attribute__((address_space(3))) unsigned int*)(dst + 8192), 16, 0, 0);
}

template<int MB, int NB>
__device__ __forceinline__ void mquad(f4v (&acc)[8][4],
                                      const s8v (&a)[4][2],
                                      const s8v (&b)[4][2])
{
    #pragma unroll
    for (int mi = 0; mi < 4; ++mi)
        #pragma unroll
        for (int nj = 0; nj < 2; ++nj)
            #pragma unroll
            for (int ks = 0; ks < 2; ++ks)
                acc[MB + mi][NB + nj] = __builtin_amdgcn_mfma_f32_16x16x32_bf16(
                    a[mi][ks], b[NB + nj][ks], acc[MB + mi][NB + nj], 0, 0, 0);
}

__global__ void __launch_bounds__(512, 2) gemm256_bf16_mfma(
    const ushort_t* __restrict__ A, int lda,
    const ushort_t* __restrict__ B, int ldb,
    int K,
    void* __restrict__ C0v, void* __restrict__ C1v, int splitN, int ldc,
    const float* __restrict__ bias, int act, int store_bf16)
{
    __shared__ __align__(16) ushort_t smem[65536];   // 128 KiB: A ring | B ring
    char* sb = (char*)smem;

    const int tid  = threadIdx.x;
    const int lane = tid & 63;
    const int w    = tid >> 6;            // wave 0..7
    const int wm   = w & 1;               // M-wave: rows wm*128..+127
    const int wn   = w >> 1;              // N-wave: cols wn*64..+63

    // bijective XCD patch swizzle for the 16x16 grid (T1): hardware assigns
    // xcd = bid%8; give each XCD an 8x4 patch (8 B-panels + 4 A-panels).
    int bx = blockIdx.x, by = blockIdx.y;
    if (gridDim.x == 16 && gridDim.y == 16) {
        const int bid = blockIdx.y * 16 + blockIdx.x;
        const int xcd = bid & 7;
        const int j   = bid >> 3;         // 0..31
        bx = (xcd & 1) * 8 + (j & 7);
        by = (xcd >> 1) * 4 + (j >> 3);
    }
    const int m0 = by * 256;
    const int n0 = bx * 256;

    const int fr   = lane & 15;
    const int kg   = lane >> 4;           // k-chunk 0..3 (8 elems)
    const int NT   = K >> 6;              // K-tiles (BK=64); requires NT >= 3

    // --- per-thread staging bases (hoisted; st_16x32 pre-swizzled source) ---
    const int  sr  = tid >> 2;                                        // 0..127
    const int  ske = (((tid & 3) << 4) ^ (((tid >> 5) & 1) << 5)) >> 1; // elems
    const ushort_t* aBase = A + (size_t)(m0 + sr) * lda + ske;
    const ushort_t* bBase = B + (size_t)(n0 + sr) * ldb + ske;
    char* ringA = sb;
    char* ringB = sb + 65536;
    const int woff = w << 10;

    // swizzled per-lane ds_read byte offset within a [128][32]-elem panel
    const int laneoff = fr * 64 + ((kg * 16) ^ ((fr & 8) << 2));
    const int halfB   = wn >> 1;          // which B half this wave reads

    f4v acc[8][4] = {};
    s8v a[4][2], b[4][2];

    // ---- prologue: prime 7 half-tiles (tile0 full + 3 of tile1) ----
    stage_t<0>(bBase, ldb, 0, ringB, woff);
    stage_t<1>(bBase, ldb, 0, ringB, woff);
    stage_t<2>(aBase, lda, 0, ringA, woff);
    stage_t<3>(aBase, lda, 0, ringA, woff);
    stage_t<0>(bBase, ldb, 1, ringB, woff);
    stage_t<1>(bBase, ldb, 1, ringB, woff);
    stage_t<2>(aBase, lda, 1, ringA, woff);
    asm volatile("s_waitcnt vmcnt(6)" ::: "memory");   // tile 0 fully landed
    __builtin_amdgcn_s_barrier();

    for (int t = 0; t < NT; ++t) {
        const int slotA = ((t << 1) + wm) & 3;
        const int slotB = ((t << 1) + halfB) & 3;
        const char* sa = ringA + slotA * 16384;
        const char* sB = ringB + slotB * 16384 + ((wn & 1) << 12);

        // ---- P1: ds_read A(mi0-3)+B(all); stage t+1.A1 ----
        #pragma unroll
        for (int mi = 0; mi < 4; ++mi)
            #pragma unroll
            for (int ks = 0; ks < 2; ++ks)
                a[mi][ks] = *reinterpret_cast<const s8v*>(
                    sa + ks * 8192 + mi * 1024 + laneoff);
        #pragma unroll
        for (int nj = 0; nj < 4; ++nj)
            #pragma unroll
            for (int ks = 0; ks < 2; ++ks)
                b[nj][ks] = *reinterpret_cast<const s8v*>(
                    sB + ks * 8192 + nj * 1024 + laneoff);
        if (t + 1 < NT) stage_t<3>(aBase, lda, t + 1, ringA, woff);
        __builtin_amdgcn_s_barrier();
        asm volatile("s_waitcnt lgkmcnt(0)" ::: "memory");
        __builtin_amdgcn_sched_barrier(0);
        __builtin_amdgcn_s_setprio(1);
        mquad<0, 0>(acc, a, b);
        __builtin_amdgcn_s_setprio(0);
        __builtin_amdgcn_s_barrier();

        // ---- P2: stage t+2.B0 (slot held tile t B0, read done in P1) ----
        if (t + 2 < NT) stage_t<0>(bBase, ldb, t + 2, ringB, woff);
        __builtin_amdgcn_s_barrier();
        __builtin_amdgcn_s_setprio(1);
        mquad<0, 2>(acc, a, b);
        __builtin_amdgcn_s_setprio(0);
        __builtin_amdgcn_s_barrier();

        // ---- P3: ds_read A(mi4-7); stage t+2.B1 ----
        #pragma unroll
        for (int mi = 0; mi < 4; ++mi)
            #pragma unroll
            for (int ks = 0; ks < 2; ++ks)
                a[mi][ks] = *reinterpret_cast<const s8v*>(
                    sa + ks * 8192 + (mi + 4) * 1024 + laneoff);
        if (t + 2 < NT) stage_t<1>(bBase, ldb, t + 2, ringB, woff);
        __builtin_amdgcn_s_barrier();
        asm volatile("s_waitcnt lgkmcnt(0)" ::: "memory");
        __builtin_amdgcn_sched_barrier(0);
        __builtin_amdgcn_s_setprio(1);
        mquad<4, 0>(acc, a, b);
        __builtin_amdgcn_s_setprio(0);
        __builtin_amdgcn_s_barrier();

        // ---- P4: stage t+2.A0 (slot held tile t A0, read done in P3) ----
        if (t + 2 < NT) stage_t<2>(aBase, lda, t + 2, ringA, woff);
        __builtin_amdgcn_s_barrier();
        __builtin_amdgcn_s_setprio(1);
        mquad<4, 2>(acc, a, b);
        __builtin_amdgcn_s_setprio(0);
        // K-tile boundary: counted drain -> tile t+1 guaranteed landed
        if (t < NT - 2) {
            asm volatile("s_waitcnt vmcnt(6)" ::: "memory");
            __builtin_amdgcn_s_barrier();
        } else if (t == NT - 2) {
            asm volatile("s_waitcnt vmcnt(0)" ::: "memory");
            __builtin_amdgcn_s_barrier();
        }
        // t == NT-1: last tile, epilogue follows (no LDS reuse)
    }

    // epilogue: C/D layout col=lane&15, row=(lane>>4)*4+reg  [m89]
    const int rbase = (lane >> 4) * 4;
    const int cbase = lane & 15;
    #pragma unroll
    for (int mi = 0; mi < 8; ++mi) {
        #pragma unroll
        for (int nj = 0; nj < 4; ++nj) {
            const int row = m0 + wm * 128 + mi * 16 + rbase;
            const int col = n0 + wn * 64 + nj * 16 + cbase;
            void* Cp = C0v;
            int c2 = col;
            if (C1v && col >= splitN) { Cp = C1v; c2 = col - splitN; }
            const float bv = bias ? bias[col] : 0.f;
            #pragma unroll
            for (int r = 0; r < 4; ++r) {
                float v = acc[mi][nj][r] + bv;
                if (act == 1) v = siluf(v);
                else if (act == 2) v = softplusf(v);
                if (store_bf16)
                    ((ushort_t*)Cp)[(size_t)(row + r) * ldc + c2] = f32_to_bf16(v);
                else
                    ((float*)Cp)[(size_t)(row + r) * ldc + c2] = v;
            }
        }
    }
}

// -------------------------------------------------------------------------
// 64x128-tile variant for the N<=2048 GEMMs (dt_proj/out_proj/final).
// 512 threads = 8 waves, 2x4 wave grid, 32x32/wave, acc[2][2].
// -------------------------------------------------------------------------
#define UM 64
#define UN 128

__global__ __launch_bounds__(512) void gemm64_bf16_mfma(
    const ushort_t* __restrict__ A, int lda,
    const ushort_t* __restrict__ B, int ldb,
    int K,
    void* __restrict__ C0v, int ldc,
    const float* __restrict__ bias, int act, int store_bf16)
{
    __shared__ __align__(16) ushort_t As[UM * TBK];   // 4 KB
    __shared__ __align__(16) ushort_t Bs[UN * TBK];   // 8 KB

    const int tid  = threadIdx.x;
    const int lane = tid & 63;
    const int w    = tid >> 6;            // wave 0..7
    const int wm   = w & 1;               // wave row (0..1) -> 32 rows
    const int wn   = w >> 1;              // wave col (0..3) -> 32 cols
    const int m0   = blockIdx.y * UM;
    const int n0   = blockIdx.x * UN;

    const int srow = lane >> 2;
    const int scol = (lane & 3) * 8;

    f4v acc[2][2] = {};

    for (int k0 = 0; k0 < K; k0 += TBK) {
        if (w < 4) {   // A chunks 0..3 (64 rows)
            const ushort_t* ga = A + (size_t)(m0 + w * 16 + srow) * lda + k0 + scol;
            __builtin_amdgcn_global_load_lds(
                (const __attribute__((address_space(1))) unsigned int*)ga,
                (__attribute__((address_space(3))) unsigned int*)(As + w * 512),
                16, 0, 0);
        }
        {   // B chunks 0..7 (128 rows)
            const ushort_t* gb = B + (size_t)(n0 + w * 16 + srow) * ldb + k0 + scol;
            __builtin_amdgcn_global_load_lds(
                (const __attribute__((address_space(1))) unsigned int*)gb,
                (__attribute__((address_space(3))) unsigned int*)(Bs + w * 512),
                16, 0, 0);
        }
        __syncthreads();

        const int fr = lane & 15;
        const int kg = lane >> 4;
        s8v a[2], b[2];
        #pragma unroll
        for (int t = 0; t < 2; ++t)
            a[t] = *reinterpret_cast<const s8v*>(As + (wm * 32 + t * 16 + fr) * TBK + kg * 8);
        #pragma unroll
        for (int t = 0; t < 2; ++t)
            b[t] = *reinterpret_cast<const s8v*>(Bs + (wn * 32 + t * 16 + fr) * TBK + kg * 8);
        #pragma unroll
        for (int i = 0; i < 2; ++i)
            #pragma unroll
            for (int j = 0; j < 2; ++j)
                acc[i][j] = __builtin_amdgcn_mfma_f32_16x16x32_bf16(
                    a[i], b[j], acc[i][j], 0, 0, 0);
        __syncthreads();
    }

    const int rbase = (lane >> 4) * 4;
    const int cbase = lane & 15;
    #pragma unroll
    for (int i = 0; i < 2; ++i) {
        #pragma unroll
        for (int j = 0; j < 2; ++j) {
            const int row = m0 + wm * 32 + i * 16 + rbase;
            const int col = n0 + wn * 32 + j * 16 + cbase;
            const float bv = bias ? bias[col] : 0.f;
            #pragma unroll
            for (int r = 0; r < 4; ++r) {
                float v = acc[i][j][r] + bv;
                if (act == 1) v = siluf(v);
                else if (act == 2) v = softplusf(v);
                if (store_bf16)
                    ((ushort_t*)C0v)[(size_t)(row + r) * ldc + col] = f32_to_bf16(v);
                else
                    ((float*)C0v)[(size_t)(row + r) * ldc + col] = v;
            }
        }
    }
}

// -------------------------------------------------------------------------
// x_proj skinny GEMM, split-K with fp32 atomic reduction.
// -------------------------------------------------------------------------
__global__ __launch_bounds__(256) void xproj_mfma(
    const ushort_t* __restrict__ A, const ushort_t* __restrict__ Bw,
    float* __restrict__ Cout)
{
    __shared__ __align__(16) ushort_t As[64 * 32];   // 4 KB
    __shared__ __align__(16) ushort_t Bs[96 * 32];   // 6 KB

    const int tid = threadIdx.x;
    const int lane = tid & 63;
    const int w = tid >> 6;
    const int kbase = blockIdx.x * XKC;
    const int m0 = blockIdx.y * 64;

    const int srow = lane >> 2;
    const int scol = (lane & 3) * 8;

    f4v acc[6] = {};

    for (int k0 = kbase; k0 < kbase + XKC; k0 += 32) {
        {
            const ushort_t* ga = A + (size_t)(m0 + w * 16 + srow) * DINNER + k0 + scol;
            __builtin_amdgcn_global_load_lds(
                (const __attribute__((address_space(1))) unsigned int*)ga,
                (__attribute__((address_space(3))) unsigned int*)(As + (w * 16) * 32),
                16, 0, 0);
        }
        {
            const ushort_t* gb = Bw + (size_t)(w * 16 + srow) * DINNER + k0 + scol;
            __builtin_amdgcn_global_load_lds(
                (const __attribute__((address_space(1))) unsigned int*)gb,
                (__attribute__((address_space(3))) unsigned int*)(Bs + (w * 16) * 32),
                16, 0, 0);
        }
        if (w < 2) {
            const ushort_t* gb = Bw + (size_t)((4 + w) * 16 + srow) * DINNER + k0 + scol;
            __builtin_amdgcn_global_load_lds(
                (const __attribute__((address_space(1))) unsigned int*)gb,
                (__attribute__((address_space(3))) unsigned int*)(Bs + ((4 + w) * 16) * 32),
                16, 0, 0);
        }
        __syncthreads();

        const int fr = lane & 15;
        const int kg = lane >> 4;
        const s8v a = *reinterpret_cast<const s8v*>(As + (w * 16 + fr) * 32 + kg * 8);
        #pragma unroll
        for (int j = 0; j < 6; ++j) {
            const s8v b = *reinterpret_cast<const s8v*>(Bs + (j * 16 + fr) * 32 + kg * 8);
            acc[j] = __builtin_amdgcn_mfma_f32_16x16x32_bf16(a, b, acc[j], 0, 0, 0);
        }
        __syncthreads();
    }

    const int rbase = (lane >> 4) * 4;
    const int cb = lane & 15;
    #pragma unroll
    for (int j = 0; j < 6; ++j)
        #pragma unroll
        for (int r = 0; r < 4; ++r)
            atomicAdd(&Cout[(size_t)(m0 + w * 16 + rbase + r) * XPROJ_N + j * 16 + cb],
                      acc[j][r]);
}

// -------------------------------------------------------------------------
// Causal depthwise conv1d (W=4) + bias + SiLU; bf16 in, bf16 out.
// -------------------------------------------------------------------------
__global__ __launch_bounds__(256) void conv_silu_kernel(
    const ushort_t* __restrict__ xin, const float* __restrict__ w,
    const float* __restrict__ b, ushort_t* __restrict__ xcbf)
{
    const int idx = blockIdx.x * blockDim.x + threadIdx.x;
    const int c = idx % DINNER;
    const int bl = idx / DINNER;
    const int l = bl % LL;
    const int bb = bl / LL;
    if (bb >= BB) return;

    const ushort_t* xp = xin + (size_t)bb * LL * DINNER + c;
    float acc = b[c];
    #pragma unroll
    for (int k = 0; k < DCONV; ++k) {
        const int ll = l - (DCONV - 1) + k;
        if (ll >= 0)
            acc = fmaf(bf16_to_f32(xp[(size_t)ll * DINNER]), w[c * DCONV + k], acc);
    }
    xcbf[idx] = f32_to_bf16(siluf(acc));
}

// -------------------------------------------------------------------------
// Segmented selective scan, SEG=64, 16 states/thread (round-8 form).
// Grid (DINNER/256, SEG, BB) = 1024 blocks = 4 waves/SIMD.
// B/C via converged global float4 loads (L1 broadcast).
// -------------------------------------------------------------------------
__global__ __launch_bounds__(256) void scan_part1(
    const ushort_t* __restrict__ delta, const float* __restrict__ xdbl,
    const ushort_t* __restrict__ xc, const float* __restrict__ A_log,
    float* __restrict__ hloc, float* __restrict__ decay)
{
    const int d = blockIdx.x * 256 + threadIdx.x;
    const int seg = blockIdx.y;
    const int b = blockIdx.z;
    const int t0 = seg * LS;

    float Ad[DSTATE];
    #pragma unroll
    for (int n = 0; n < DSTATE; ++n)
        Ad[n] = -expf(A_log[d * DSTATE + n]);

    float h[DSTATE];
    #pragma unroll
    for (int n = 0; n < DSTATE; ++n) h[n] = 0.f;

    const ushort_t* dp = delta + ((size_t)b * LL) * DINNER + d;
    const ushort_t* up = xc    + ((size_t)b * LL) * DINNER + d;
    const float*    xb = xdbl  + ((size_t)b * LL) * XPROJ_N;

    float sum_dl = 0.f;
    for (int t = t0; t < t0 + LS; ++t) {
        const float dl = bf16_to_f32(dp[(size_t)t * DINNER]);
        const float u  = bf16_to_f32(up[(size_t)t * DINNER]);
        const float4 b0 = *reinterpret_cast<const float4*>(&xb[t * XPROJ_N + DTRANK + 0]);
        const float4 b1 = *reinterpret_cast<const float4*>(&xb[t * XPROJ_N + DTRANK + 4]);
        const float4 b2 = *reinterpret_cast<const float4*>(&xb[t * XPROJ_N + DTRANK + 8]);
        const float4 b3 = *reinterpret_cast<const float4*>(&xb[t * XPROJ_N + DTRANK + 12]);
        const float Bv[DSTATE] = {b0.x, b0.y, b0.z, b0.w, b1.x, b1.y, b1.z, b1.w,
                                  b2.x, b2.y, b2.z, b2.w, b3.x, b3.y, b3.z, b3.w};
        const float dlu = dl * u;
        sum_dl += dl;
        #pragma unroll
        for (int n = 0; n < DSTATE; ++n)
            h[n] = __expf(dl * Ad[n]) * h[n] + dlu * Bv[n];
    }

    const size_t base = (((size_t)b * SEG + seg) * DSTATE) * DINNER + d;
    #pragma unroll
    for (int n = 0; n < DSTATE; ++n) {
        hloc[base + (size_t)n * DINNER]  = h[n];
        decay[base + (size_t)n * DINNER] = __expf(Ad[n] * sum_dl);
    }
}

// In-place combine: hloc[s] is REPLACED by the true h_start of segment s.
__global__ __launch_bounds__(256) void scan_combine(
    float* __restrict__ hloc, const float* __restrict__ decay)
{
    const int idx = blockIdx.x * 256 + threadIdx.x;
    const int d = idx % DINNER;
    const int n = (idx / DINNER) % DSTATE;
    const int b = idx / (DINNER * DSTATE);
    if (b >= BB) return;

    float carry = 0.f;
    for (int s = 0; s < SEG; ++s) {
        const size_t off = (((size_t)b * SEG + s) * DSTATE + n) * DINNER + d;
        const float hl = hloc[off];
        hloc[off] = carry;
        carry = decay[off] * carry + hl;
    }
}

__global__ __launch_bounds__(256) void scan_part2(
    const ushort_t* __restrict__ delta, const float* __restrict__ xdbl,
    const ushort_t* __restrict__ xc, const ushort_t* __restrict__ z,
    const float* __restrict__ A_log, const float* __restrict__ Dvec,
    const float* __restrict__ hstart, ushort_t* __restrict__ ybf)
{
    const int d = blockIdx.x * 256 + threadIdx.x;
    const int seg = blockIdx.y;
    const int b = blockIdx.z;
    const int t0 = seg * LS;

    float Ad[DSTATE];
    #pragma unroll
    for (int n = 0; n < DSTATE; ++n)
        Ad[n] = -expf(A_log[d * DSTATE + n]);

    float h[DSTATE];
    const size_t hbase = (((size_t)b * SEG + seg) * DSTATE) * DINNER + d;
    #pragma unroll
    for (int n = 0; n < DSTATE; ++n)
        h[n] = hstart[hbase + (size_t)n * DINNER];

    const float Dd = Dvec[d];
    const ushort_t* dp = delta + ((size_t)b * LL) * DINNER + d;
    const ushort_t* up = xc    + ((size_t)b * LL) * DINNER + d;
    const float*    xb = xdbl  + ((size_t)b * LL) * XPROJ_N;
    const ushort_t* zp = z     + ((size_t)b * LL) * DINNER + d;
    ushort_t*       yp = ybf   + ((size_t)b * LL) * DINNER + d;

    for (int t = t0; t < t0 + LS; ++t) {
        const float dl = bf16_to_f32(dp[(size_t)t * DINNER]);
        const float u  = bf16_to_f32(up[(size_t)t * DINNER]);
        const float zv = bf16_to_f32(zp[(size_t)t * DINNER]);
        const float4 b0 = *reinterpret_cast<const float4*>(&xb[t * XPROJ_N + DTRANK + 0]);
        const float4 b1 = *reinterpret_cast<const float4*>(&xb[t * XPROJ_N + DTRANK + 4]);
        const float4 b2 = *reinterpret_cast<const float4*>(&xb[t * XPROJ_N + DTRANK + 8]);
        const float4 b3 = *reinterpret_cast<const float4*>(&xb[t * XPROJ_N + DTRANK + 12]);
        const float4 c0 = *reinterpret_cast<const float4*>(&xb[t * XPROJ_N + DTRANK + DSTATE + 0]);
        const float4 c1 = *reinterpret_cast<const float4*>(&xb[t * XPROJ_N + DTRANK + DSTATE + 4]);
        const float4 c2 = *reinterpret_cast<const float4*>(&xb[t * XPROJ_N + DTRANK + DSTATE + 8]);
        const float4 c3 = *reinterpret_cast<const float4*>(&xb[t * XPROJ_N + DTRANK + DSTATE + 12]);
        const float Bv[DSTATE] = {b0.x, b0.y, b0.z, b0.w, b1.x, b1.y, b1.z, b1.w,
                                  b2.x, b2.y, b2.z, b2.w, b3.x, b3.y, b3.z, b3.w};
        const float Cv[DSTATE] = {c0.x, c0.y, c0.z, c0.w, c1.x, c1.y, c1.z, c1.w,
                                  c2.x, c2.y, c2.z, c2.w, c3.x, c3.y, c3.z, c3.w};
        const float dlu = dl * u;
        float y = 0.f;
        #pragma unroll
        for (int n = 0; n < DSTATE; ++n) {
            h[n] = __expf(dl * Ad[n]) * h[n] + dlu * Bv[n];
            y = fmaf(h[n], Cv[n], y);
        }
        yp[(size_t)t * DINNER] = f32_to_bf16((y + u * Dd) * siluf(zv));
    }
}

// -------------------------------------------------------------------------
extern "C" void kernel_launch(void* const* d_in, const int* in_sizes, int n_in,
                              void* d_out, int out_size, void* d_ws, size_t ws_size,
                              hipStream_t stream) {
    const float* x         = (const float*)d_in[0];
    const float* in_proj_w = (const float*)d_in[1];
    const float* conv_w    = (const float*)d_in[2];
    const float* conv_b    = (const float*)d_in[3];
    const float* x_proj_w  = (const float*)d_in[4];
    const float* dt_proj_w = (const float*)d_in[5];
    const float* dt_proj_b = (const float*)d_in[6];
    const float* A_log     = (const float*)d_in[7];
    const float* Dvec      = (const float*)d_in[8];
    const float* ssm_out_w = (const float*)d_in[9];
    const float* final_w   = (const float*)d_in[10];
    const float* final_b   = (const float*)d_in[11];
    float* out = (float*)d_out;

    // ---- workspace layout, 126 MB total ----
    const size_t MB = 1024 * 1024;
    char* base = (char*)d_ws;
    ushort_t* xin_bf   = (ushort_t*)(base);              // 16 MB [in_proj -> conv]
    ushort_t* z_bf     = (ushort_t*)(base + 16 * MB);    // 16 MB [in_proj -> scan2]
    ushort_t* xc_bf    = (ushort_t*)(base + 32 * MB);    // 16 MB [conv -> xproj/scan]
    ushort_t* delta_bf = (ushort_t*)(base + 48 * MB);    // 16 MB [dt_proj -> scan]
    float*    xdbl     = (float*)(base + 64 * MB);       // 1.5 MB [xproj -> scan]
    ushort_t* x_bf     = (ushort_t*)(base + 78 * MB);    // 8 MB [prep -> in_proj]
    ushort_t* ipw_bf   = (ushort_t*)(base + 86 * MB);    // 8 MB [prep -> in_proj]
    ushort_t* sow_bf   = (ushort_t*)(base + 94 * MB);    // 4 MB
    ushort_t* fw_bf    = (ushort_t*)(base + 98 * MB);    // 2 MB
    ushort_t* xpw_bf   = (ushort_t*)(base + 100 * MB);   // 384 KB
    ushort_t* dtw_bf   = (ushort_t*)(base + 100 * MB + 512 * 1024);  // 256 KB
    ushort_t* dt_bf    = (ushort_t*)(base + 101 * MB);   // 512 KB
    ushort_t* y_bf     = (ushort_t*)(base + 102 * MB);   // 16 MB
    ushort_t* outb_bf  = (ushort_t*)(base + 118 * MB);   // 8 MB
    // scan scratch (16 MB each), OVERLAID on dead regions:
    float* hloc  = (float*)(base);            // 16 MB over xin_bf (dead after conv)
    float* decay = (float*)(base + 78 * MB);  // 16 MB over x_bf/ipw_bf (dead after in_proj)

    // 0) fused casts + xdbl zeroing (one launch; 11968 blocks)
    prep_kernel<<<11968, 256, 0, stream>>>(
        x, in_proj_w, ssm_out_w, final_w, x_proj_w, dt_proj_w,
        x_bf, ipw_bf, sow_bf, fw_bf, xpw_bf, dtw_bf, (float4*)xdbl);

    // 1) in_proj (256^2 8-phase MFMA): [xin_bf | z_bf] = x @ in_proj_w^T
    //    (M=4096, N=4096, K=1024; grid 16x16 = 256 blocks = 1/CU)
    gemm256_bf16_mfma<<<dim3((2 * DINNER) / 256, MROWS / 256), 512, 0, stream>>>(
        x_bf, DMODEL, ipw_bf, DMODEL, DMODEL,
        xin_bf, z_bf, DINNER, DINNER, nullptr, 0, 1);

    // 2) causal depthwise conv + SiLU -> xc_bf
    conv_silu_kernel<<<(MROWS * DINNER) / 256, 256, 0, stream>>>(
        xin_bf, conv_w, conv_b, xc_bf);

    // 3) x_proj (bf16 MFMA, split-K atomic): xdbl = xc @ x_proj_w^T (M=4096,N=96,K=2048)
    xproj_mfma<<<dim3(XKSPLIT, MROWS / 64), 256, 0, stream>>>(xc_bf, xpw_bf, xdbl);

    // 4) dt_proj (bf16 MFMA, 64-row tile): delta_bf = softplus(dt @ dt_proj_w^T + b)
    cast_dt_kernel<<<(MROWS * DTRANK / 4) / 256, 256, 0, stream>>>(xdbl, dt_bf);
    gemm64_bf16_mfma<<<dim3(DINNER / UN, MROWS / UM), 512, 0, stream>>>(
        dt_bf, DTRANK, dtw_bf, DTRANK, DTRANK,
        delta_bf, DINNER, dt_proj_b, 2, 1);

    // 5) segmented selective scan + skip + gate -> y_bf
    scan_part1<<<dim3(DINNER / 256, SEG, BB), 256, 0, stream>>>(
        delta_bf, xdbl, xc_bf, A_log, hloc, decay);
    scan_combine<<<(BB * DSTATE * DINNER) / 256, 256, 0, stream>>>(hloc, decay);
    scan_part2<<<dim3(DINNER / 256, SEG, BB), 256, 0, stream>>>(
        delta_bf, xdbl, xc_bf, z_bf, A_log, Dvec, hloc, y_bf);

    // 6) out_proj (bf16 MFMA, 64-row tile): outb_bf = y @ ssm_out_w^T (M=4096,N=1024,K=2048)
    gemm64_bf16_mfma<<<dim3(DMODEL / UN, MROWS / UM), 512, 0, stream>>>(
        y_bf, DINNER, sow_bf, DINNER, DINNER,
        outb_bf, DMODEL, nullptr, 0, 1);

    // 7) final (bf16 MFMA, 64-row tile): out = silu(outb @ final_w^T + final_b)
    gemm64_bf16_mfma<<<dim3(DMODEL / UN, MROWS / UM), 512, 0, stream>>>(
        outb_bf, DMODEL, fw_bf, DMODEL, DMODEL,
        out, DMODEL, final_b, 1, 0);
}

// Round 4
// 395.193 us; speedup vs baseline: 1.0903x; 1.0760x over previous
//
#include <hip/hip_runtime.h>
#include <hip/hip_bf16.h>
#include <math.h>

// Problem constants (from reference)
#define BB 2
#define LL 2048
#define DMODEL 1024
#define DINNER 2048
#define DSTATE 16
#define DCONV 4
#define DTRANK 64
#define MROWS (BB * LL)          // 4096
#define XPROJ_N (DTRANK + 2 * DSTATE)  // 96

// scan segmentation: SEG=64, 16 states/thread, 1024 blocks = 4 waves/SIMD.
#define SEG 64
#define LS (LL / SEG)            // 32

// x_proj split-K
#define XKSPLIT 8
#define XKC (DINNER / XKSPLIT)   // 256

typedef unsigned short ushort_t;
typedef short s8v __attribute__((ext_vector_type(8)));   // 8 x bf16 (4 VGPRs)
typedef float f4v __attribute__((ext_vector_type(4)));   // 4 x fp32 acc

__device__ __forceinline__ float siluf(float x) {
    return x / (1.f + expf(-x));
}
__device__ __forceinline__ float softplusf(float x) {
    return fmaxf(x, 0.f) + log1pf(expf(-fabsf(x)));
}
__device__ __forceinline__ ushort_t f32_to_bf16(float f) {
    unsigned u = __builtin_bit_cast(unsigned, f);
    unsigned r = (u + 0x7FFFu + ((u >> 16) & 1u)) >> 16;   // RNE
    return (ushort_t)r;
}
__device__ __forceinline__ float bf16_to_f32(ushort_t u) {
    return __builtin_bit_cast(float, ((unsigned)u) << 16);
}

// -------------------------------------------------------------------------
// Fused prep: all fp32->bf16 weight/input casts + xdbl zeroing, one launch.
// -------------------------------------------------------------------------
__global__ __launch_bounds__(256) void prep_kernel(
    const float* __restrict__ x, const float* __restrict__ ipw,
    const float* __restrict__ sow, const float* __restrict__ fw,
    const float* __restrict__ xpw, const float* __restrict__ dtw,
    ushort_t* __restrict__ x_bf, ushort_t* __restrict__ ipw_bf,
    ushort_t* __restrict__ sow_bf, ushort_t* __restrict__ fw_bf,
    ushort_t* __restrict__ xpw_bf, ushort_t* __restrict__ dtw_bf,
    float4* __restrict__ xdbl_zero)
{
    const long i = ((long)blockIdx.x * 256 + threadIdx.x) * 4;
    const float* src; ushort_t* dst; long off;
    if      (i < 4194304L)  { src = x;   dst = x_bf;   off = i; }
    else if (i < 8388608L)  { src = ipw; dst = ipw_bf; off = i - 4194304L; }
    else if (i < 10485760L) { src = sow; dst = sow_bf; off = i - 8388608L; }
    else if (i < 11534336L) { src = fw;  dst = fw_bf;  off = i - 10485760L; }
    else if (i < 11730944L) { src = xpw; dst = xpw_bf; off = i - 11534336L; }
    else if (i < 11862016L) { src = dtw; dst = dtw_bf; off = i - 11730944L; }
    else { xdbl_zero[(i - 11862016L) >> 2] = make_float4(0.f, 0.f, 0.f, 0.f); return; }
    const float4 v = *reinterpret_cast<const float4*>(src + off);
    ushort_t o[4] = {f32_to_bf16(v.x), f32_to_bf16(v.y),
                     f32_to_bf16(v.z), f32_to_bf16(v.w)};
    *reinterpret_cast<uint2*>(dst + off) = *reinterpret_cast<uint2*>(o);
}

// cast xdbl[:, 0:64] (ld 96, fp32) -> dt_bf [MROWS,64]
__global__ __launch_bounds__(256) void cast_dt_kernel(
    const float* __restrict__ xdbl, ushort_t* __restrict__ dtbf)
{
    const int i4 = (blockIdx.x * 256 + threadIdx.x) * 4;   // over MROWS*64
    const int row = i4 >> 6;
    const int col = i4 & 63;
    const float4 v = *reinterpret_cast<const float4*>(&xdbl[(size_t)row * XPROJ_N + col]);
    ushort_t o[4] = {f32_to_bf16(v.x), f32_to_bf16(v.y),
                     f32_to_bf16(v.z), f32_to_bf16(v.w)};
    *reinterpret_cast<uint2*>(dtbf + i4) = *reinterpret_cast<uint2*>(o);
}

// -------------------------------------------------------------------------
// bf16 MFMA GEMM, 128x128 tile, 512 threads = 8 waves (2x4 wave grid,
// 64x32/wave, acc[4][2]). Known-good round-0 kernel (measured 680 TF on
// in_proj, MfmaUtil 27%, WRITE_SIZE clean). Used for ALL dense GEMMs:
// in_proj / dt_proj / out_proj / final. The 256^2 8-phase port was removed:
// two rounds (r1/r2) showed a stable ~1KB/thread scratch anomaly (WRITE_SIZE
// 164MB vs 33.5MB, MfmaUtil halved) that survived a full de-templatization;
// under 2 waves/SIMD the 256-reg budget can't hold acc[8][4]+frags+epilogue.
// Split output: cols >= splitN go to C1 at (col - splitN).
// -------------------------------------------------------------------------
#define TM 128
#define TN 128
#define TBK 32

__global__ __launch_bounds__(512) void gemm_bf16_mfma(
    const ushort_t* __restrict__ A, int lda,
    const ushort_t* __restrict__ B, int ldb,
    int K,
    void* __restrict__ C0v, void* __restrict__ C1v, int splitN, int ldc,
    const float* __restrict__ bias, int act, int store_bf16)
{
    __shared__ __align__(16) ushort_t As[TM * TBK];   // 8 KB
    __shared__ __align__(16) ushort_t Bs[TN * TBK];   // 8 KB

    const int tid  = threadIdx.x;
    const int lane = tid & 63;
    const int w    = tid >> 6;            // wave 0..7
    const int wm   = w & 1;               // wave row (0..1) -> 64 rows
    const int wn   = w >> 1;              // wave col (0..3) -> 32 cols
    const int m0   = blockIdx.y * TM;
    const int n0   = blockIdx.x * TN;

    const int srow = lane >> 2;           // 0..15
    const int scol = (lane & 3) * 8;      // bf16 elems: 0,8,16,24

    f4v acc[4][2] = {};

    for (int k0 = 0; k0 < K; k0 += TBK) {
        {
            const ushort_t* ga = A + (size_t)(m0 + w * 16 + srow) * lda + k0 + scol;
            __builtin_amdgcn_global_load_lds(
                (const __attribute__((address_space(1))) unsigned int*)ga,
                (__attribute__((address_space(3))) unsigned int*)(As + w * 512),
                16, 0, 0);
        }
        {
            const ushort_t* gb = B + (size_t)(n0 + w * 16 + srow) * ldb + k0 + scol;
            __builtin_amdgcn_global_load_lds(
                (const __attribute__((address_space(1))) unsigned int*)gb,
                (__attribute__((address_space(3))) unsigned int*)(Bs + w * 512),
                16, 0, 0);
        }
        __syncthreads();

        const int fr = lane & 15;
        const int kg = lane >> 4;         // k-group 0..3 (8 elems each)
        s8v a[4], b[2];
        #pragma unroll
        for (int t = 0; t < 4; ++t)
            a[t] = *reinterpret_cast<const s8v*>(As + (wm * 64 + t * 16 + fr) * TBK + kg * 8);
        #pragma unroll
        for (int t = 0; t < 2; ++t)
            b[t] = *reinterpret_cast<const s8v*>(Bs + (wn * 32 + t * 16 + fr) * TBK + kg * 8);
        #pragma unroll
        for (int i = 0; i < 4; ++i)
            #pragma unroll
            for (int j = 0; j < 2; ++j)
                acc[i][j] = __builtin_amdgcn_mfma_f32_16x16x32_bf16(
                    a[i], b[j], acc[i][j], 0, 0, 0);
        __syncthreads();
    }

    // epilogue: C/D layout col=lane&15, row=(lane>>4)*4+reg  [m89]
    const int rbase = (lane >> 4) * 4;
    const int cbase = lane & 15;
    #pragma unroll
    for (int i = 0; i < 4; ++i) {
        #pragma unroll
        for (int j = 0; j < 2; ++j) {
            const int row = m0 + wm * 64 + i * 16 + rbase;
            const int col = n0 + wn * 32 + j * 16 + cbase;
            void* Cp = C0v;
            int c2 = col;
            if (C1v && col >= splitN) { Cp = C1v; c2 = col - splitN; }
            const float bv = bias ? bias[col] : 0.f;
            #pragma unroll
            for (int r = 0; r < 4; ++r) {
                float v = acc[i][j][r] + bv;
                if (act == 1) v = siluf(v);
                else if (act == 2) v = softplusf(v);
                if (store_bf16)
                    ((ushort_t*)Cp)[(size_t)(row + r) * ldc + c2] = f32_to_bf16(v);
                else
                    ((float*)Cp)[(size_t)(row + r) * ldc + c2] = v;
            }
        }
    }
}

// -------------------------------------------------------------------------
// x_proj skinny GEMM, split-K with fp32 atomic reduction.
// -------------------------------------------------------------------------
__global__ __launch_bounds__(256) void xproj_mfma(
    const ushort_t* __restrict__ A, const ushort_t* __restrict__ Bw,
    float* __restrict__ Cout)
{
    __shared__ __align__(16) ushort_t As[64 * 32];   // 4 KB
    __shared__ __align__(16) ushort_t Bs[96 * 32];   // 6 KB

    const int tid = threadIdx.x;
    const int lane = tid & 63;
    const int w = tid >> 6;
    const int kbase = blockIdx.x * XKC;
    const int m0 = blockIdx.y * 64;

    const int srow = lane >> 2;
    const int scol = (lane & 3) * 8;

    f4v acc[6] = {};

    for (int k0 = kbase; k0 < kbase + XKC; k0 += 32) {
        {
            const ushort_t* ga = A + (size_t)(m0 + w * 16 + srow) * DINNER + k0 + scol;
            __builtin_amdgcn_global_load_lds(
                (const __attribute__((address_space(1))) unsigned int*)ga,
                (__attribute__((address_space(3))) unsigned int*)(As + (w * 16) * 32),
                16, 0, 0);
        }
        {
            const ushort_t* gb = Bw + (size_t)(w * 16 + srow) * DINNER + k0 + scol;
            __builtin_amdgcn_global_load_lds(
                (const __attribute__((address_space(1))) unsigned int*)gb,
                (__attribute__((address_space(3))) unsigned int*)(Bs + (w * 16) * 32),
                16, 0, 0);
        }
        if (w < 2) {
            const ushort_t* gb = Bw + (size_t)((4 + w) * 16 + srow) * DINNER + k0 + scol;
            __builtin_amdgcn_global_load_lds(
                (const __attribute__((address_space(1))) unsigned int*)gb,
                (__attribute__((address_space(3))) unsigned int*)(Bs + ((4 + w) * 16) * 32),
                16, 0, 0);
        }
        __syncthreads();

        const int fr = lane & 15;
        const int kg = lane >> 4;
        const s8v a = *reinterpret_cast<const s8v*>(As + (w * 16 + fr) * 32 + kg * 8);
        #pragma unroll
        for (int j = 0; j < 6; ++j) {
            const s8v b = *reinterpret_cast<const s8v*>(Bs + (j * 16 + fr) * 32 + kg * 8);
            acc[j] = __builtin_amdgcn_mfma_f32_16x16x32_bf16(a, b, acc[j], 0, 0, 0);
        }
        __syncthreads();
    }

    const int rbase = (lane >> 4) * 4;
    const int cb = lane & 15;
    #pragma unroll
    for (int j = 0; j < 6; ++j)
        #pragma unroll
        for (int r = 0; r < 4; ++r)
            atomicAdd(&Cout[(size_t)(m0 + w * 16 + rbase + r) * XPROJ_N + j * 16 + cb],
                      acc[j][r]);
}

// -------------------------------------------------------------------------
// Causal depthwise conv1d (W=4) + bias + SiLU; bf16 in, bf16 out.
// -------------------------------------------------------------------------
__global__ __launch_bounds__(256) void conv_silu_kernel(
    const ushort_t* __restrict__ xin, const float* __restrict__ w,
    const float* __restrict__ b, ushort_t* __restrict__ xcbf)
{
    const int idx = blockIdx.x * blockDim.x + threadIdx.x;
    const int c = idx % DINNER;
    const int bl = idx / DINNER;
    const int l = bl % LL;
    const int bb = bl / LL;
    if (bb >= BB) return;

    const ushort_t* xp = xin + (size_t)bb * LL * DINNER + c;
    float acc = b[c];
    #pragma unroll
    for (int k = 0; k < DCONV; ++k) {
        const int ll = l - (DCONV - 1) + k;
        if (ll >= 0)
            acc = fmaf(bf16_to_f32(xp[(size_t)ll * DINNER]), w[c * DCONV + k], acc);
    }
    xcbf[idx] = f32_to_bf16(siluf(acc));
}

// -------------------------------------------------------------------------
// Segmented selective scan, SEG=64, 16 states/thread (round-8 form).
// Grid (DINNER/256, SEG, BB) = 1024 blocks = 4 waves/SIMD.
// B/C via converged global float4 loads (L1 broadcast).
// -------------------------------------------------------------------------
__global__ __launch_bounds__(256) void scan_part1(
    const ushort_t* __restrict__ delta, const float* __restrict__ xdbl,
    const ushort_t* __restrict__ xc, const float* __restrict__ A_log,
    float* __restrict__ hloc, float* __restrict__ decay)
{
    const int d = blockIdx.x * 256 + threadIdx.x;
    const int seg = blockIdx.y;
    const int b = blockIdx.z;
    const int t0 = seg * LS;

    float Ad[DSTATE];
    #pragma unroll
    for (int n = 0; n < DSTATE; ++n)
        Ad[n] = -expf(A_log[d * DSTATE + n]);

    float h[DSTATE];
    #pragma unroll
    for (int n = 0; n < DSTATE; ++n) h[n] = 0.f;

    const ushort_t* dp = delta + ((size_t)b * LL) * DINNER + d;
    const ushort_t* up = xc    + ((size_t)b * LL) * DINNER + d;
    const float*    xb = xdbl  + ((size_t)b * LL) * XPROJ_N;

    float sum_dl = 0.f;
    for (int t = t0; t < t0 + LS; ++t) {
        const float dl = bf16_to_f32(dp[(size_t)t * DINNER]);
        const float u  = bf16_to_f32(up[(size_t)t * DINNER]);
        const float4 b0 = *reinterpret_cast<const float4*>(&xb[t * XPROJ_N + DTRANK + 0]);
        const float4 b1 = *reinterpret_cast<const float4*>(&xb[t * XPROJ_N + DTRANK + 4]);
        const float4 b2 = *reinterpret_cast<const float4*>(&xb[t * XPROJ_N + DTRANK + 8]);
        const float4 b3 = *reinterpret_cast<const float4*>(&xb[t * XPROJ_N + DTRANK + 12]);
        const float Bv[DSTATE] = {b0.x, b0.y, b0.z, b0.w, b1.x, b1.y, b1.z, b1.w,
                                  b2.x, b2.y, b2.z, b2.w, b3.x, b3.y, b3.z, b3.w};
        const float dlu = dl * u;
        sum_dl += dl;
        #pragma unroll
        for (int n = 0; n < DSTATE; ++n)
            h[n] = __expf(dl * Ad[n]) * h[n] + dlu * Bv[n];
    }

    const size_t base = (((size_t)b * SEG + seg) * DSTATE) * DINNER + d;
    #pragma unroll
    for (int n = 0; n < DSTATE; ++n) {
        hloc[base + (size_t)n * DINNER]  = h[n];
        decay[base + (size_t)n * DINNER] = __expf(Ad[n] * sum_dl);
    }
}

// In-place combine: hloc[s] is REPLACED by the true h_start of segment s.
__global__ __launch_bounds__(256) void scan_combine(
    float* __restrict__ hloc, const float* __restrict__ decay)
{
    const int idx = blockIdx.x * 256 + threadIdx.x;
    const int d = idx % DINNER;
    const int n = (idx / DINNER) % DSTATE;
    const int b = idx / (DINNER * DSTATE);
    if (b >= BB) return;

    float carry = 0.f;
    for (int s = 0; s < SEG; ++s) {
        const size_t off = (((size_t)b * SEG + s) * DSTATE + n) * DINNER + d;
        const float hl = hloc[off];
        hloc[off] = carry;
        carry = decay[off] * carry + hl;
    }
}

__global__ __launch_bounds__(256) void scan_part2(
    const ushort_t* __restrict__ delta, const float* __restrict__ xdbl,
    const ushort_t* __restrict__ xc, const ushort_t* __restrict__ z,
    const float* __restrict__ A_log, const float* __restrict__ Dvec,
    const float* __restrict__ hstart, ushort_t* __restrict__ ybf)
{
    const int d = blockIdx.x * 256 + threadIdx.x;
    const int seg = blockIdx.y;
    const int b = blockIdx.z;
    const int t0 = seg * LS;

    float Ad[DSTATE];
    #pragma unroll
    for (int n = 0; n < DSTATE; ++n)
        Ad[n] = -expf(A_log[d * DSTATE + n]);

    float h[DSTATE];
    const size_t hbase = (((size_t)b * SEG + seg) * DSTATE) * DINNER + d;
    #pragma unroll
    for (int n = 0; n < DSTATE; ++n)
        h[n] = hstart[hbase + (size_t)n * DINNER];

    const float Dd = Dvec[d];
    const ushort_t* dp = delta + ((size_t)b * LL) * DINNER + d;
    const ushort_t* up = xc    + ((size_t)b * LL) * DINNER + d;
    const float*    xb = xdbl  + ((size_t)b * LL) * XPROJ_N;
    const ushort_t* zp = z     + ((size_t)b * LL) * DINNER + d;
    ushort_t*       yp = ybf   + ((size_t)b * LL) * DINNER + d;

    for (int t = t0; t < t0 + LS; ++t) {
        const float dl = bf16_to_f32(dp[(size_t)t * DINNER]);
        const float u  = bf16_to_f32(up[(size_t)t * DINNER]);
        const float zv = bf16_to_f32(zp[(size_t)t * DINNER]);
        const float4 b0 = *reinterpret_cast<const float4*>(&xb[t * XPROJ_N + DTRANK + 0]);
        const float4 b1 = *reinterpret_cast<const float4*>(&xb[t * XPROJ_N + DTRANK + 4]);
        const float4 b2 = *reinterpret_cast<const float4*>(&xb[t * XPROJ_N + DTRANK + 8]);
        const float4 b3 = *reinterpret_cast<const float4*>(&xb[t * XPROJ_N + DTRANK + 12]);
        const float4 c0 = *reinterpret_cast<const float4*>(&xb[t * XPROJ_N + DTRANK + DSTATE + 0]);
        const float4 c1 = *reinterpret_cast<const float4*>(&xb[t * XPROJ_N + DTRANK + DSTATE + 4]);
        const float4 c2 = *reinterpret_cast<const float4*>(&xb[t * XPROJ_N + DTRANK + DSTATE + 8]);
        const float4 c3 = *reinterpret_cast<const float4*>(&xb[t * XPROJ_N + DTRANK + DSTATE + 12]);
        const float Bv[DSTATE] = {b0.x, b0.y, b0.z, b0.w, b1.x, b1.y, b1.z, b1.w,
                                  b2.x, b2.y, b2.z, b2.w, b3.x, b3.y, b3.z, b3.w};
        const float Cv[DSTATE] = {c0.x, c0.y, c0.z, c0.w, c1.x, c1.y, c1.z, c1.w,
                                  c2.x, c2.y, c2.z, c2.w, c3.x, c3.y, c3.z, c3.w};
        const float dlu = dl * u;
        float y = 0.f;
        #pragma unroll
        for (int n = 0; n < DSTATE; ++n) {
            h[n] = __expf(dl * Ad[n]) * h[n] + dlu * Bv[n];
            y = fmaf(h[n], Cv[n], y);
        }
        yp[(size_t)t * DINNER] = f32_to_bf16((y + u * Dd) * siluf(zv));
    }
}

// -------------------------------------------------------------------------
extern "C" void kernel_launch(void* const* d_in, const int* in_sizes, int n_in,
                              void* d_out, int out_size, void* d_ws, size_t ws_size,
                              hipStream_t stream) {
    const float* x         = (const float*)d_in[0];
    const float* in_proj_w = (const float*)d_in[1];
    const float* conv_w    = (const float*)d_in[2];
    const float* conv_b    = (const float*)d_in[3];
    const float* x_proj_w  = (const float*)d_in[4];
    const float* dt_proj_w = (const float*)d_in[5];
    const float* dt_proj_b = (const float*)d_in[6];
    const float* A_log     = (const float*)d_in[7];
    const float* Dvec      = (const float*)d_in[8];
    const float* ssm_out_w = (const float*)d_in[9];
    const float* final_w   = (const float*)d_in[10];
    const float* final_b   = (const float*)d_in[11];
    float* out = (float*)d_out;

    // ---- workspace layout, 126 MB total ----
    const size_t MB = 1024 * 1024;
    char* base = (char*)d_ws;
    ushort_t* xin_bf   = (ushort_t*)(base);              // 16 MB [in_proj -> conv]
    ushort_t* z_bf     = (ushort_t*)(base + 16 * MB);    // 16 MB [in_proj -> scan2]
    ushort_t* xc_bf    = (ushort_t*)(base + 32 * MB);    // 16 MB [conv -> xproj/scan]
    ushort_t* delta_bf = (ushort_t*)(base + 48 * MB);    // 16 MB [dt_proj -> scan]
    float*    xdbl     = (float*)(base + 64 * MB);       // 1.5 MB [xproj -> scan]
    ushort_t* x_bf     = (ushort_t*)(base + 78 * MB);    // 8 MB [prep -> in_proj]
    ushort_t* ipw_bf   = (ushort_t*)(base + 86 * MB);    // 8 MB [prep -> in_proj]
    ushort_t* sow_bf   = (ushort_t*)(base + 94 * MB);    // 4 MB
    ushort_t* fw_bf    = (ushort_t*)(base + 98 * MB);    // 2 MB
    ushort_t* xpw_bf   = (ushort_t*)(base + 100 * MB);   // 384 KB
    ushort_t* dtw_bf   = (ushort_t*)(base + 100 * MB + 512 * 1024);  // 256 KB
    ushort_t* dt_bf    = (ushort_t*)(base + 101 * MB);   // 512 KB
    ushort_t* y_bf     = (ushort_t*)(base + 102 * MB);   // 16 MB
    ushort_t* outb_bf  = (ushort_t*)(base + 118 * MB);   // 8 MB
    // scan scratch (16 MB each), OVERLAID on dead regions:
    float* hloc  = (float*)(base);            // 16 MB over xin_bf (dead after conv)
    float* decay = (float*)(base + 78 * MB);  // 16 MB over x_bf/ipw_bf (dead after in_proj)

    // 0) fused casts + xdbl zeroing (one launch; 11968 blocks)
    prep_kernel<<<11968, 256, 0, stream>>>(
        x, in_proj_w, ssm_out_w, final_w, x_proj_w, dt_proj_w,
        x_bf, ipw_bf, sow_bf, fw_bf, xpw_bf, dtw_bf, (float4*)xdbl);

    // 1) in_proj (bf16 MFMA): [xin_bf | z_bf] = x @ in_proj_w^T  (M=4096,N=4096,K=1024)
    gemm_bf16_mfma<<<dim3(2 * DINNER / TN, MROWS / TM), 512, 0, stream>>>(
        x_bf, DMODEL, ipw_bf, DMODEL, DMODEL,
        xin_bf, z_bf, DINNER, DINNER, nullptr, 0, 1);

    // 2) causal depthwise conv + SiLU -> xc_bf
    conv_silu_kernel<<<(MROWS * DINNER) / 256, 256, 0, stream>>>(
        xin_bf, conv_w, conv_b, xc_bf);

    // 3) x_proj (bf16 MFMA, split-K atomic): xdbl = xc @ x_proj_w^T (M=4096,N=96,K=2048)
    xproj_mfma<<<dim3(XKSPLIT, MROWS / 64), 256, 0, stream>>>(xc_bf, xpw_bf, xdbl);

    // 4) dt_proj (bf16 MFMA, 128-tile): delta_bf = softplus(dt @ dt_proj_w^T + b)
    cast_dt_kernel<<<(MROWS * DTRANK / 4) / 256, 256, 0, stream>>>(xdbl, dt_bf);
    gemm_bf16_mfma<<<dim3(DINNER / TN, MROWS / TM), 512, 0, stream>>>(
        dt_bf, DTRANK, dtw_bf, DTRANK, DTRANK,
        delta_bf, nullptr, 0, DINNER, dt_proj_b, 2, 1);

    // 5) segmented selective scan + skip + gate -> y_bf
    scan_part1<<<dim3(DINNER / 256, SEG, BB), 256, 0, stream>>>(
        delta_bf, xdbl, xc_bf, A_log, hloc, decay);
    scan_combine<<<(BB * DSTATE * DINNER) / 256, 256, 0, stream>>>(hloc, decay);
    scan_part2<<<dim3(DINNER / 256, SEG, BB), 256, 0, stream>>>(
        delta_bf, xdbl, xc_bf, z_bf, A_log, Dvec, hloc, y_bf);

    // 6) out_proj (bf16 MFMA, 128-tile): outb_bf = y @ ssm_out_w^T (M=4096,N=1024,K=2048)
    gemm_bf16_mfma<<<dim3(DMODEL / TN, MROWS / TM), 512, 0, stream>>>(
        y_bf, DINNER, sow_bf, DINNER, DINNER,
        outb_bf, nullptr, 0, DMODEL, nullptr, 0, 1);

    // 7) final (bf16 MFMA, 128-tile): out = silu(outb @ final_w^T + final_b)
    gemm_bf16_mfma<<<dim3(DMODEL / TN, MROWS / TM), 512, 0, stream>>>(
        outb_bf, DMODEL, fw_bf, DMODEL, DMODEL,
        out, nullptr, 0, DMODEL, final_b, 1, 0);
}